// Round 3
// baseline (816.212 us; speedup 1.0000x reference)
//
#include <hip/hip_runtime.h>

#define KSTATE 64
#define NSAMP  1024

__device__ __forceinline__ float bcast0(float x) {
  return __int_as_float(__builtin_amdgcn_readfirstlane(__float_as_int(x)));
}
__device__ __forceinline__ float rlane(float x, int l) {
  return __int_as_float(__builtin_amdgcn_readlane(__float_as_int(x), l));
}

// One wave (64 threads): row-softmax of T -> expT, log_softmax(pi) -> log_pi, zero out.
__global__ __launch_bounds__(64) void hmm_preproc(
    const float* __restrict__ pi, const float* __restrict__ T,
    float* __restrict__ expT, float* __restrict__ log_pi,
    float* __restrict__ out) {
  const int lane = threadIdx.x;
  float m = -3.4e38f;
  for (int k = 0; k < KSTATE; ++k) m = fmaxf(m, T[lane * KSTATE + k]);
  float s = 0.f;
  for (int k = 0; k < KSTATE; ++k) s += __expf(T[lane * KSTATE + k] - m);
  float inv = 1.0f / s;
  for (int k = 0; k < KSTATE; ++k)
    expT[lane * KSTATE + k] = __expf(T[lane * KSTATE + k] - m) * inv;
  float x = pi[lane];
  float mm = x;
  #pragma unroll
  for (int off = 32; off >= 1; off >>= 1) mm = fmaxf(mm, __shfl_xor(mm, off, 64));
  float e = __expf(x - mm);
  #pragma unroll
  for (int off = 32; off >= 1; off >>= 1) e += __shfl_xor(e, off, 64);
  log_pi[lane] = x - mm - __logf(e);
  if (lane == 0) out[0] = 0.f;  // harness poisons d_out; we atomicAdd into it
}

// One wave per sequence, scaled-linear-domain forward recurrence.
//
// Broadcast strategy (round 3): j=0..15 via v_readlane (pure VALU, gives the
// DS pipe time to deliver), j=16..63 via ds_bpermute_b32 with a wave-uniform
// index = a direct full-wave broadcast of a[j] from the live VGPR.
//   - no LDS store->load roundtrip (round-0 stall, ~240 cyc exposed)
//   - no SGPR-write hazard chains   (round-2 stall, ~4+ cyc/readlane)
//   - bpermute issues on the LGKM pipe and OVERLAPS the VALU fma stream;
//     compiler staggers lgkmcnt waits per consumer.
__global__ __launch_bounds__(256, 1) void hmm_forward(
    const float* __restrict__ log_pdf,
    const float* __restrict__ expT,
    const float* __restrict__ log_pi,
    float* __restrict__ out, int N) {
  const int lane = threadIdx.x & 63;
  const int wave = threadIdx.x >> 6;
  const int b = blockIdx.x * 4 + wave;

  // tcol[j] = expT[j][lane]  (column `lane` of the transition matrix)
  float tcol[KSTATE];
  #pragma unroll
  for (int j = 0; j < KSTATE; ++j) tcol[j] = expT[j * KSTATE + lane];

  // Opaque zero index register so 4*j folds into the DS offset field
  // (keeps one addr VGPR instead of 48 materialized index constants).
  int ib;
  __asm__ volatile("v_mov_b32 %0, 0" : "=v"(ib));

  const float* lp = log_pdf + (size_t)lane * (size_t)N + (size_t)b * NSAMP;

  float4 v0 = *(const float4*)(lp);        // group 0 (t=0..3)
  float4 r1 = *(const float4*)(lp + 4);
  float4 r2 = *(const float4*)(lp + 8);
  float4 r3 = *(const float4*)(lp + 12);

  float x0 = v0.x + log_pi[lane];
  float C = bcast0(x0);
  float a = __expf(x0 - C);

#define STEP(E) do {                                                          \
    const int ai_ = __float_as_int(a);                                        \
    float bb[48];                                                             \
    _Pragma("unroll")                                                         \
    for (int q = 0; q < 48; ++q)                                              \
      bb[q] = __int_as_float(                                                 \
          __builtin_amdgcn_ds_bpermute(ib + 4 * (16 + q), ai_));              \
    float c[8];                                                               \
    _Pragma("unroll")                                                         \
    for (int q = 0; q < 8; ++q) c[q] = rlane(a, q) * tcol[q];                 \
    _Pragma("unroll")                                                         \
    for (int q = 0; q < 8; ++q) c[q] = fmaf(rlane(a, 8 + q), tcol[8 + q], c[q]); \
    _Pragma("unroll")                                                         \
    for (int q = 0; q < 48; ++q)                                              \
      c[q & 7] = fmaf(bb[q], tcol[16 + q], c[q & 7]);                         \
    float sA = (c[0] + c[1]) + (c[2] + c[3]);                                 \
    float sB = (c[4] + c[5]) + (c[6] + c[7]);                                 \
    a = (sA + sB) * (E);                                                      \
  } while (0)

  // Renorm every 4 steps (range analysis: 4-step growth/decay stays well
  // inside fp32; identical math to the verified earlier rounds).
#define RENORM() do {                                                         \
    float c = bcast0(a);                                                      \
    a = a * __builtin_amdgcn_rcpf(c);                                         \
    C += __logf(c);                                                           \
  } while (0)

  {  // steps t = 1..3 from group 0
    float e1 = __expf(v0.y), e2 = __expf(v0.z), e3 = __expf(v0.w);
    STEP(e1); STEP(e2); STEP(e3);
    RENORM();
  }

  const int NG = NSAMP / 4;
  for (int g = 1; g < NG; ++g) {
    float4 v = r1; r1 = r2; r2 = r3;
    int gn = (g + 3 < NG) ? (g + 3) : (NG - 1);
    r3 = *(const float4*)(lp + 4 * gn);
    float e0 = __expf(v.x), e1 = __expf(v.y), e2 = __expf(v.z), e3 = __expf(v.w);
    STEP(e0); STEP(e1); STEP(e2); STEP(e3);
    RENORM();
  }
#undef STEP
#undef RENORM

  // out += C + log(sum_k a[k])
  float s = a;
  #pragma unroll
  for (int off = 32; off >= 1; off >>= 1) s += __shfl_xor(s, off, 64);
  if (lane == 0) atomicAdd(out, C + __logf(s));
}

extern "C" void kernel_launch(void* const* d_in, const int* in_sizes, int n_in,
                              void* d_out, int out_size, void* d_ws, size_t ws_size,
                              hipStream_t stream) {
  const float* log_pdf = (const float*)d_in[0];
  const float* pi      = (const float*)d_in[1];
  const float* T       = (const float*)d_in[2];
  float* out = (float*)d_out;

  float* expT   = (float*)d_ws;              // 64*64 floats
  float* log_pi = expT + KSTATE * KSTATE;    // 64 floats

  const int N = in_sizes[0] / KSTATE;        // 1048576
  const int B = N / NSAMP;                   // 1024 sequences

  hipLaunchKernelGGL(hmm_preproc, dim3(1), dim3(64), 0, stream,
                     pi, T, expT, log_pi, out);
  hipLaunchKernelGGL(hmm_forward, dim3(B / 4), dim3(256), 0, stream,
                     log_pdf, expT, log_pi, out, N);
}

// Round 4
// 527.574 us; speedup vs baseline: 1.5471x; 1.5471x over previous
//
#include <hip/hip_runtime.h>

#define KSTATE 64
#define NSAMP  1024

__device__ __forceinline__ float bcast0(float x) {
  return __int_as_float(__builtin_amdgcn_readfirstlane(__float_as_int(x)));
}
__device__ __forceinline__ float rlane(float x, int l) {
  return __int_as_float(__builtin_amdgcn_readlane(__float_as_int(x), l));
}

// One wave (64 threads): row-softmax of T -> expT, log_softmax(pi) -> log_pi, zero out.
__global__ __launch_bounds__(64) void hmm_preproc(
    const float* __restrict__ pi, const float* __restrict__ T,
    float* __restrict__ expT, float* __restrict__ log_pi,
    float* __restrict__ out) {
  const int lane = threadIdx.x;
  float m = -3.4e38f;
  for (int k = 0; k < KSTATE; ++k) m = fmaxf(m, T[lane * KSTATE + k]);
  float s = 0.f;
  for (int k = 0; k < KSTATE; ++k) s += __expf(T[lane * KSTATE + k] - m);
  float inv = 1.0f / s;
  for (int k = 0; k < KSTATE; ++k)
    expT[lane * KSTATE + k] = __expf(T[lane * KSTATE + k] - m) * inv;
  float x = pi[lane];
  float mm = x;
  #pragma unroll
  for (int off = 32; off >= 1; off >>= 1) mm = fmaxf(mm, __shfl_xor(mm, off, 64));
  float e = __expf(x - mm);
  #pragma unroll
  for (int off = 32; off >= 1; off >>= 1) e += __shfl_xor(e, off, 64);
  log_pi[lane] = x - mm - __logf(e);
  if (lane == 0) out[0] = 0.f;  // harness poisons d_out; we atomicAdd into it
}

// One wave per sequence, scaled-linear-domain forward recurrence.
//
// Round-4 broadcast strategy: batched v_readlane with enforced scheduling
// distance. Calibration from rounds 0/2/3 (VALUBusy decomposition):
//   plain fma = 2 cyc; DPP-fmac ~ 6 cyc; rl adjacent to consumer ~10.5 cyc
//   (SGPR-write -> VALU-read hazard); DS broadcast ops ~23 cyc (dead).
// So: issue ALL 32 readlanes of a half, sched_barrier(0), then the 32 fmas.
// Every fma reads an SGPR written >=32 instrs earlier -> no hazard stalls.
// 8 accumulator chains hide fma latency. Pure VALU, no LDS/DPP/DS.
__global__ __launch_bounds__(256, 1) void hmm_forward(
    const float* __restrict__ log_pdf,
    const float* __restrict__ expT,
    const float* __restrict__ log_pi,
    float* __restrict__ out, int N) {
  const int lane = threadIdx.x & 63;
  const int wave = threadIdx.x >> 6;
  const int b = blockIdx.x * 4 + wave;

  // tcol[j] = expT[j][lane]  (column `lane` of the transition matrix)
  float tcol[KSTATE];
  #pragma unroll
  for (int j = 0; j < KSTATE; ++j) tcol[j] = expT[j * KSTATE + lane];

  const float* lp = log_pdf + (size_t)lane * (size_t)N + (size_t)b * NSAMP;

  float4 v0 = *(const float4*)(lp);        // group 0 (t=0..3)
  float4 r1 = *(const float4*)(lp + 4);
  float4 r2 = *(const float4*)(lp + 8);
  float4 r3 = *(const float4*)(lp + 12);

  float x0 = v0.x + log_pi[lane];
  float C = bcast0(x0);
  float a = __expf(x0 - C);

#define STEP(E) do {                                                          \
    float sv_[32];                                                            \
    float c_[8];                                                              \
    /* phase A1: broadcast a[0..31] into uniform (SGPR) temps */              \
    _Pragma("unroll")                                                         \
    for (int q = 0; q < 32; ++q) sv_[q] = rlane(a, q);                        \
    __builtin_amdgcn_sched_barrier(0);                                        \
    /* phase B1: 32 fmas, 8 chains; distance to rl >= 32 instrs */            \
    _Pragma("unroll")                                                         \
    for (int q = 0; q < 8; ++q) c_[q] = sv_[q] * tcol[q];                     \
    _Pragma("unroll")                                                         \
    for (int q = 8; q < 32; ++q) c_[q & 7] = fmaf(sv_[q], tcol[q], c_[q & 7]);\
    __builtin_amdgcn_sched_barrier(0);                                        \
    /* phase A2: broadcast a[32..63] */                                       \
    _Pragma("unroll")                                                         \
    for (int q = 0; q < 32; ++q) sv_[q] = rlane(a, 32 + q);                   \
    __builtin_amdgcn_sched_barrier(0);                                        \
    /* phase B2 */                                                            \
    _Pragma("unroll")                                                         \
    for (int q = 0; q < 32; ++q)                                              \
      c_[q & 7] = fmaf(sv_[q], tcol[32 + q], c_[q & 7]);                      \
    float sA = (c_[0] + c_[1]) + (c_[2] + c_[3]);                             \
    float sB = (c_[4] + c_[5]) + (c_[6] + c_[7]);                             \
    a = (sA + sB) * (E);                                                      \
  } while (0)

  // Renorm every 4 steps (range analysis: 4-step growth/decay stays well
  // inside fp32; identical math to the verified earlier rounds).
#define RENORM() do {                                                         \
    float c = bcast0(a);                                                      \
    a = a * __builtin_amdgcn_rcpf(c);                                         \
    C += __logf(c);                                                           \
  } while (0)

  {  // steps t = 1..3 from group 0
    float e1 = __expf(v0.y), e2 = __expf(v0.z), e3 = __expf(v0.w);
    STEP(e1); STEP(e2); STEP(e3);
    RENORM();
  }

  const int NG = NSAMP / 4;
  for (int g = 1; g < NG; ++g) {
    float4 v = r1; r1 = r2; r2 = r3;
    int gn = (g + 3 < NG) ? (g + 3) : (NG - 1);
    r3 = *(const float4*)(lp + 4 * gn);
    float e0 = __expf(v.x), e1 = __expf(v.y), e2 = __expf(v.z), e3 = __expf(v.w);
    STEP(e0); STEP(e1); STEP(e2); STEP(e3);
    RENORM();
  }
#undef STEP
#undef RENORM

  // out += C + log(sum_k a[k])
  float s = a;
  #pragma unroll
  for (int off = 32; off >= 1; off >>= 1) s += __shfl_xor(s, off, 64);
  if (lane == 0) atomicAdd(out, C + __logf(s));
}

extern "C" void kernel_launch(void* const* d_in, const int* in_sizes, int n_in,
                              void* d_out, int out_size, void* d_ws, size_t ws_size,
                              hipStream_t stream) {
  const float* log_pdf = (const float*)d_in[0];
  const float* pi      = (const float*)d_in[1];
  const float* T       = (const float*)d_in[2];
  float* out = (float*)d_out;

  float* expT   = (float*)d_ws;              // 64*64 floats
  float* log_pi = expT + KSTATE * KSTATE;    // 64 floats

  const int N = in_sizes[0] / KSTATE;        // 1048576
  const int B = N / NSAMP;                   // 1024 sequences

  hipLaunchKernelGGL(hmm_preproc, dim3(1), dim3(64), 0, stream,
                     pi, T, expT, log_pi, out);
  hipLaunchKernelGGL(hmm_forward, dim3(B / 4), dim3(256), 0, stream,
                     log_pdf, expT, log_pi, out, N);
}